// Round 10
// baseline (125.428 us; speedup 1.0000x reference)
//
#include <hip/hip_runtime.h>
#include <hip/hip_fp16.h>
#include <math.h>

typedef _Float16 f16;
typedef __attribute__((ext_vector_type(8))) _Float16 f16x8;
typedef __attribute__((ext_vector_type(4))) _Float16 f16x4;
typedef __attribute__((ext_vector_type(4))) float f32x4;
typedef __attribute__((ext_vector_type(16))) float f32x16;
typedef unsigned int u32;

#define NB 16
#define NN 2048
#define ND 256
#define KVB 32
#define XSZ ((size_t)NB * NN * ND)   // 8388608 elements

__device__ __forceinline__ void gll16(const void* g, void* l) {
    __builtin_amdgcn_global_load_lds(
        (const __attribute__((address_space(1))) unsigned int*)g,
        (__attribute__((address_space(3))) unsigned int*)l, 16, 0, 0);
}

__device__ __forceinline__ long long len_at(const int* lenp, int b, bool is64) {
    return is64 ? ((const long long*)lenp)[b] : (long long)lenp[b];
}

__device__ __forceinline__ float bperm_f(int src_lane, float v) {
    return __int_as_float(__builtin_amdgcn_ds_bpermute(src_lane * 4, __float_as_int(v)));
}

// ---------------- pre-pass: X fp32 -> Xh f16 [b][n][d] + Xt f16 [b][d][n] ----
__global__ __launch_bounds__(256)
void prep(const float* __restrict__ X, f16* __restrict__ Xh, f16* __restrict__ Xt)
{
    const int b  = blockIdx.z;
    const int n0 = blockIdx.x * 64;
    const int d0 = blockIdx.y * 64;
    const int t  = threadIdx.x;
    __shared__ f16 T[64][72];

    const float* Xb  = X  + ((size_t)b*NN + n0)*ND + d0;
    f16*         Xhb = Xh + ((size_t)b*NN + n0)*ND + d0;
    #pragma unroll
    for (int it = 0; it < 4; ++it) {
        int r  = it*16 + (t >> 4);
        int c4 = t & 15;
        float4 v = *(const float4*)(Xb + (size_t)r*ND + c4*4);
        f16x4 h; h[0]=(f16)v.x; h[1]=(f16)v.y; h[2]=(f16)v.z; h[3]=(f16)v.w;
        *(f16x4*)&Xhb[(size_t)r*ND + c4*4] = h;
        *(f16x4*)&T[r][c4*4] = h;
    }
    __syncthreads();
    f16* Xtb = Xt + ((size_t)b*ND + d0)*NN + n0;
    #pragma unroll
    for (int it = 0; it < 2; ++it) {
        int id = it*256 + t;
        int dr = id >> 3;
        int ch = id & 7;
        f16x8 v;
        #pragma unroll
        for (int u = 0; u < 8; ++u) v[u] = T[ch*8+u][dr];
        *(f16x8*)&Xtb[(size_t)dr*NN + ch*8] = v;
    }
}

// ---------------- attn9: 32x32x16 swapped flash, 4 waves x 32q, split-KV ----
// QK^T: S^T = mfma(K_frag, Q_frag) accumulated over 16 k-steps. C-layout:
//   q = lane&31, j = (reg&3) + 8*(reg>>2) + 4*(lane>>5). Softmax per q-row is
//   15 in-lane fmax + shfl_xor(32); m,l per-lane scalars (dup across hi).
// P repack to PV A-frag (row=q=lane&31, k=j=hi*8+i) entirely in registers:
//   8 f16-pack + 4 shfl_xor(32); frag(s) = hi ? [recv, quad(2s+1)]
//                                         : [quad(2s), recv].
// PV: O = mfma(P_frag, V_frag): C row=q, col=d -> direct store.
// LDS: K 16KB + V 16KB, frag-order slots, single-buffered, 3-barrier pipeline.
__global__ __launch_bounds__(256, 1)
void attn9(const f16* __restrict__ Xh, const f16* __restrict__ Xt,
           const int* __restrict__ lenp,
           f16* __restrict__ Op, float* __restrict__ Sl)
{
    const int tid  = threadIdx.x;
    const int lane = tid & 63;
    const int w  = tid >> 6;
    const int cl = lane & 31;
    const int hi = lane >> 5;

    // ---- job mapping: LPT + XCD pairing + KV-half split (512 blocks) ----
    const bool is64 = (lenp[1] == 0);
    long long Lv[NB];
    #pragma unroll
    for (int i = 0; i < NB; ++i) Lv[i] = len_at(lenp, i, is64);
    const int x   = blockIdx.x & 7;
    const int kk2 = blockIdx.x >> 3;      // 0..63
    const int h   = kk2 & 1;              // KV half (tile parity)
    const int k2  = kk2 >> 1;             // 0..31
    const int wanted = (k2 < 16) ? x : (15 - x);
    const int qt  = k2 & 15;
    int bsel = 0; long long Lb = 1;
    #pragma unroll
    for (int bb = 0; bb < NB; ++bb) {
        int rk = 0;
        #pragma unroll
        for (int b2 = 0; b2 < NB; ++b2)
            rk += (Lv[b2] > Lv[bb]) || (Lv[b2] == Lv[bb] && b2 < bb);
        if (rk == wanted) { bsel = bb; Lb = Lv[bb]; }
    }
    const int nt  = (int)((Lb + KVB - 1) / KVB);
    const int nth = (h == 0) ? ((nt + 1) >> 1) : (nt >> 1);
    if (nth == 0) return;

    __shared__ f16 Kl[8192];   // 16KB: slot (kk*64 + j*2 + h2)*16
    __shared__ f16 Vl[8192];   // 16KB: slot ((dt*2+s)*64 + cc*2 + h2)*16

    const char* xhb = (const char*)(Xh + (size_t)bsel*NN*ND);
    const char* xtb = (const char*)(Xt + (size_t)bsel*ND*NN);

    const int q0 = qt*128 + w*32;

    // ---- Q B-frags: lane holds Q[q0+cl][kk*16 + hi*8 + i] ----
    f16x8 qf[16];
    {
        const char* qp = xhb + (size_t)(q0 + cl)*512 + hi*16;
        #pragma unroll
        for (int kk = 0; kk < 16; ++kk) qf[kk] = *(const f16x8*)(qp + kk*32);
    }

    auto stage_k = [&](int kv0) {
        char* kb = (char*)&Kl[0];
        #pragma unroll
        for (int it = 0; it < 4; ++it) {
            int S  = it*256 + tid;
            int kk = S >> 6, j = (S >> 1) & 31, h2 = S & 1;
            gll16(xhb + (size_t)(kv0 + j)*512 + kk*32 + h2*16, kb + S*16);
        }
    };
    auto stage_v = [&](int kv0) {
        char* vb = (char*)&Vl[0];
        #pragma unroll
        for (int it = 0; it < 4; ++it) {
            int T  = it*256 + tid;
            int ds = T >> 6, cc = (T >> 1) & 31, h2 = T & 1;
            int dt = ds >> 1, s = ds & 1;
            gll16(xtb + (size_t)(dt*32 + cc)*4096 + (size_t)(kv0 + s*16 + h2*8)*2,
                  vb + T*16);
        }
    };

    f32x16 o[8];
    #pragma unroll
    for (int dt = 0; dt < 8; ++dt)
        #pragma unroll
        for (int r = 0; r < 16; ++r) o[dt][r] = 0.f;
    float m = -INFINITY;
    float l = 0.f;

    stage_k(h*KVB);
    stage_v(h*KVB);

    for (int ti = 0; ti < nth; ++ti) {
        const int kv0 = (2*ti + h) * KVB;
        const bool more = (ti + 1 < nth);

        asm volatile("s_waitcnt vmcnt(4)" ::: "memory");   // own K(t) landed
        __builtin_amdgcn_s_barrier();                      // K ready block-wide

        const char* kb = (const char*)&Kl[0];
        const char* vb = (const char*)&Vl[0];

        // ---- QK^T swapped: S^T[32j x 32q], single accumulation chain ----
        f32x16 st;
        #pragma unroll
        for (int r = 0; r < 16; ++r) st[r] = 0.f;
        __builtin_amdgcn_s_setprio(1);
        #pragma unroll
        for (int kk = 0; kk < 16; ++kk) {
            f16x8 ka = *(const f16x8*)(kb + kk*1024 + cl*32 + hi*16);
            st = __builtin_amdgcn_mfma_f32_32x32x16_f16(ka, qf[kk], st, 0, 0, 0);
        }
        __builtin_amdgcn_s_setprio(0);

        asm volatile("s_waitcnt vmcnt(0)" ::: "memory");   // own V(t) landed
        __builtin_amdgcn_s_barrier();                      // V ready + K fully read
        if (more) stage_k(kv0 + 2*KVB);                    // overwrite K under SM/PV

        // ---- column mask: j(r) = (r&3) + 8*(r>>2) + 4*hi ----
        const float NEG = -1e30f;
        if (kv0 + KVB > (int)Lb) {
            #pragma unroll
            for (int r = 0; r < 16; ++r) {
                int j = kv0 + (r & 3) + 8*(r >> 2) + 4*hi;
                if (j >= (int)Lb) st[r] = NEG;
            }
        }

        // ---- online softmax, row q = cl ----
        float tm = st[0];
        #pragma unroll
        for (int r = 1; r < 16; ++r) tm = fmaxf(tm, st[r]);
        tm = fmaxf(tm, __shfl_xor(tm, 32, 64));
        if (__any(tm > m + 8.f)) {            // defer-max THR=8
            float mn = fmaxf(m, tm);
            float sc = __expf(m - mn);
            m = mn; l *= sc;
            float scr[16];
            #pragma unroll
            for (int r = 0; r < 16; ++r)
                scr[r] = bperm_f((r & 3) + 8*(r >> 2) + 4*hi, sc);
            #pragma unroll
            for (int dt = 0; dt < 8; ++dt)
                #pragma unroll
                for (int r = 0; r < 16; ++r) o[dt][r] *= scr[r];
        }
        float p[16];
        float rs = 0.f;
        #pragma unroll
        for (int r = 0; r < 16; ++r) { p[r] = __expf(st[r] - m); rs += p[r]; }
        rs += __shfl_xor(rs, 32, 64);
        l += rs;

        // ---- pack P quads and exchange across hi-halves ----
        u32 pk[8];
        #pragma unroll
        for (int Q = 0; Q < 4; ++Q) {
            f16x4 t;
            t[0]=(f16)p[4*Q+0]; t[1]=(f16)p[4*Q+1];
            t[2]=(f16)p[4*Q+2]; t[3]=(f16)p[4*Q+3];
            pk[2*Q]   = ((u32*)&t)[0];
            pk[2*Q+1] = ((u32*)&t)[1];
        }
        u32 rx0 = __shfl_xor(hi ? pk[0] : pk[2], 32, 64);
        u32 rx1 = __shfl_xor(hi ? pk[1] : pk[3], 32, 64);
        u32 rx2 = __shfl_xor(hi ? pk[4] : pk[6], 32, 64);
        u32 rx3 = __shfl_xor(hi ? pk[5] : pk[7], 32, 64);
        union { u32 u[4]; f16x8 v; } pf0, pf1;
        pf0.u[0] = hi ? rx0 : pk[0];
        pf0.u[1] = hi ? rx1 : pk[1];
        pf0.u[2] = hi ? pk[2] : rx0;
        pf0.u[3] = hi ? pk[3] : rx1;
        pf1.u[0] = hi ? rx2 : pk[4];
        pf1.u[1] = hi ? rx3 : pk[5];
        pf1.u[2] = hi ? pk[6] : rx2;
        pf1.u[3] = hi ? pk[7] : rx3;

        // ---- PV: O[32q x 256d] += P(32x32) x V(32x32d) per 32-d tile ----
        __builtin_amdgcn_s_setprio(1);
        #pragma unroll
        for (int dt = 0; dt < 8; ++dt) {
            f16x8 v0 = *(const f16x8*)(vb + (dt*2    )*1024 + cl*32 + hi*16);
            f16x8 v1 = *(const f16x8*)(vb + (dt*2 + 1)*1024 + cl*32 + hi*16);
            o[dt] = __builtin_amdgcn_mfma_f32_32x32x16_f16(pf0.v, v0, o[dt], 0, 0, 0);
            o[dt] = __builtin_amdgcn_mfma_f32_32x32x16_f16(pf1.v, v1, o[dt], 0, 0, 0);
        }
        __builtin_amdgcn_s_setprio(0);

        asm volatile("" ::: "memory");
        __builtin_amdgcn_s_barrier();                      // all done reading V(t)
        if (more) stage_v(kv0 + 2*KVB);
    }

    // ---- epilogue: normalized partial (f16) + per-row logsumexp (f32) ----
    float linv = 1.f / l;
    f16* opb = Op + (size_t)h*XSZ + ((size_t)bsel*NN + q0)*ND;
    #pragma unroll
    for (int r = 0; r < 16; ++r) {
        const int qr = (r & 3) + 8*(r >> 2) + 4*hi;
        const float inv = bperm_f(qr, linv);
        f16* row = opb + (size_t)qr*ND + cl;
        #pragma unroll
        for (int dt = 0; dt < 8; ++dt)
            row[dt*32] = (f16)(o[dt][r] * inv);
    }
    if (hi == 0) {
        Sl[((size_t)(h*NB + bsel))*NN + (size_t)(q0 + cl)] = m + __logf(l);
    }
}

// ---------------- merge: out = (O1 w1 + O2 w2) / (w1 + w2) ------------------
__global__ __launch_bounds__(256)
void merge(const f16* __restrict__ Op, const float* __restrict__ Sl,
           const int* __restrict__ lenp, float* __restrict__ out)
{
    const int tid = threadIdx.x;
    const int rg  = blockIdx.x * 8 + (tid >> 5);   // global row 0..32767
    const int b   = rg >> 11;
    const int q   = rg & 2047;
    const int d0  = (tid & 31) * 8;

    const bool is64 = (lenp[1] == 0);
    const long long Lb = len_at(lenp, b, is64);

    const f16* p1 = Op + ((size_t)b*NN + q)*ND + d0;
    f16x8 a1 = *(const f16x8*)p1;
    float r[8];
    if (Lb <= KVB) {
        #pragma unroll
        for (int i = 0; i < 8; ++i) r[i] = (float)a1[i];
    } else {
        f16x8 a2 = *(const f16x8*)(p1 + XSZ);
        float s1 = Sl[(size_t)b*NN + q];
        float s2 = Sl[(size_t)(NB + b)*NN + q];
        float sm = fmaxf(s1, s2);
        float w1 = __expf(s1 - sm), w2 = __expf(s2 - sm);
        float dn = 1.f / (w1 + w2);
        w1 *= dn; w2 *= dn;
        #pragma unroll
        for (int i = 0; i < 8; ++i) r[i] = (float)a1[i]*w1 + (float)a2[i]*w2;
    }
    float* ob = out + ((size_t)b*NN + q)*ND + d0;
    *(float4*)ob       = (float4){r[0], r[1], r[2], r[3]};
    *(float4*)(ob + 4) = (float4){r[4], r[5], r[6], r[7]};
}

// ---------------- mid-tier (round-5 attn4, proven) --------------------------
__global__ __launch_bounds__(256, 2)
void attn4(const f16* __restrict__ Xh, const f16* __restrict__ Xt,
           const int* __restrict__ lenp, float* __restrict__ out)
{
    const int tid  = threadIdx.x;
    const int lane = tid & 63;
    const int w = tid >> 6;
    const int g = lane >> 4;
    const int c = lane & 15;

    const bool is64 = (lenp[1] == 0);
    long long Lv[NB];
    #pragma unroll
    for (int i = 0; i < NB; ++i) Lv[i] = len_at(lenp, i, is64);
    const int x = blockIdx.x & 7;
    const int k = blockIdx.x >> 3;
    const int wanted = (k < 32) ? x : (15 - x);
    const int qt = k & 31;
    int bsel = 0; long long Lb = 1;
    #pragma unroll
    for (int bb = 0; bb < NB; ++bb) {
        int rk = 0;
        #pragma unroll
        for (int b2 = 0; b2 < NB; ++b2)
            rk += (Lv[b2] > Lv[bb]) || (Lv[b2] == Lv[bb] && b2 < bb);
        if (rk == wanted) { bsel = bb; Lb = Lv[bb]; }
    }
    const int nt = (int)((Lb + KVB - 1) / KVB);

    __shared__ f16 Kl[2][8192];
    __shared__ f16 Vl[2][8192];
    __shared__ f16 Pl[4][16*36];

    const char* xhb = (const char*)(Xh + (size_t)bsel*NN*ND);
    const char* xtb = (const char*)(Xt + (size_t)bsel*ND*NN);

    f16x8 qf[8];
    {
        const char* qp = xhb + (size_t)(qt*64 + w*16 + c)*512 + g*16;
        #pragma unroll
        for (int kk = 0; kk < 8; ++kk) qf[kk] = *(const f16x8*)(qp + kk*64);
    }

    auto stage = [&](int buf, int kv0) {
        char* kb = (char*)&Kl[buf][0];
        char* vb = (char*)&Vl[buf][0];
        #pragma unroll
        for (int it = 0; it < 4; ++it) {
            int S  = it*256 + tid;
            int kk = S >> 7, j = (S >> 2) & 31, gg = S & 3;
            gll16(xhb + (size_t)(kv0 + j)*512 + kk*64 + gg*16, kb + S*16);
        }
        #pragma unroll
        for (int it = 0; it < 4; ++it) {
            int T  = it*256 + tid;
            int dt = T >> 6, cc = (T >> 2) & 15, gg = T & 3;
            gll16(xtb + (size_t)(dt*16 + cc)*4096 + (size_t)(kv0 + gg*8)*2, vb + T*16);
        }
    };

    f32x4 o[16];
    #pragma unroll
    for (int dt = 0; dt < 16; ++dt) o[dt] = (f32x4){0.f,0.f,0.f,0.f};
    float m[4] = {-INFINITY,-INFINITY,-INFINITY,-INFINITY};
    float l[4] = {0.f,0.f,0.f,0.f};

    f16* pw = &Pl[w][0];

    stage(0, 0);
    if (nt > 1) stage(1, KVB);

    for (int t = 0; t < nt; ++t) {
        const int kv0 = t * KVB;
        const int buf = t & 1;

        if (t + 1 < nt) { asm volatile("s_waitcnt vmcnt(8)" ::: "memory"); }
        else            { asm volatile("s_waitcnt vmcnt(0)" ::: "memory"); }
        __builtin_amdgcn_s_barrier();

        const char* kb = (const char*)&Kl[buf][0];
        const char* vb = (const char*)&Vl[buf][0];

        f32x4 s0 = (f32x4){0.f,0.f,0.f,0.f};
        f32x4 s1 = (f32x4){0.f,0.f,0.f,0.f};
        #pragma unroll
        for (int kk = 0; kk < 8; ++kk) {
            f16x8 b0 = *(const f16x8*)(kb + kk*2048        + c*64 + g*16);
            f16x8 b1 = *(const f16x8*)(kb + kk*2048 + 1024 + c*64 + g*16);
            s0 = __builtin_amdgcn_mfma_f32_16x16x32_f16(qf[kk], b0, s0, 0, 0, 0);
            s1 = __builtin_amdgcn_mfma_f32_16x16x32_f16(qf[kk], b1, s1, 0, 0, 0);
        }

        const float NEG = -1e30f;
        if (kv0 + c >= Lb)      { s0[0]=NEG; s0[1]=NEG; s0[2]=NEG; s0[3]=NEG; }
        if (kv0 + 16 + c >= Lb) { s1[0]=NEG; s1[1]=NEG; s1[2]=NEG; s1[3]=NEG; }

        float mx[4], mn[4], sc[4], p0[4], p1[4], rs[4];
        #pragma unroll
        for (int r = 0; r < 4; ++r) mx[r] = fmaxf(s0[r], s1[r]);
        #pragma unroll
        for (int off = 8; off >= 1; off >>= 1) {
            #pragma unroll
            for (int r = 0; r < 4; ++r)
                mx[r] = fmaxf(mx[r], __shfl_xor(mx[r], off, 64));
        }
        #pragma unroll
        for (int r = 0; r < 4; ++r) {
            mn[r] = fmaxf(m[r], mx[r]);
            sc[r] = __expf(m[r] - mn[r]);
            p0[r] = __expf(s0[r] - mn[r]);
            p1[r] = __expf(s1[r] - mn[r]);
            rs[r] = p0[r] + p1[r];
        }
        #pragma unroll
        for (int off = 8; off >= 1; off >>= 1) {
            #pragma unroll
            for (int r = 0; r < 4; ++r)
                rs[r] += __shfl_xor(rs[r], off, 64);
        }
        bool chg = (sc[0]!=1.f) | (sc[1]!=1.f) | (sc[2]!=1.f) | (sc[3]!=1.f);
        if (__any(chg)) {
            #pragma unroll
            for (int dt = 0; dt < 16; ++dt) {
                o[dt][0]*=sc[0]; o[dt][1]*=sc[1]; o[dt][2]*=sc[2]; o[dt][3]*=sc[3];
            }
        }
        #pragma unroll
        for (int r = 0; r < 4; ++r) { l[r] = l[r]*sc[r] + rs[r]; m[r] = mn[r]; }

        #pragma unroll
        for (int r = 0; r < 4; ++r) {
            pw[(g*4+r)*36 + c]      = (f16)p0[r];
            pw[(g*4+r)*36 + 16 + c] = (f16)p1[r];
        }
        union { f16x4 hh[2]; f16x8 v; } pu;
        pu.hh[0] = *(const f16x4*)(pw + c*36 + g*8);
        pu.hh[1] = *(const f16x4*)(pw + c*36 + g*8 + 4);
        f16x8 pf = pu.v;

        #pragma unroll
        for (int dt = 0; dt < 16; ++dt) {
            f16x8 vf = *(const f16x8*)(vb + dt*1024 + c*64 + g*16);
            o[dt] = __builtin_amdgcn_mfma_f32_16x16x32_f16(pf, vf, o[dt], 0, 0, 0);
        }

        __builtin_amdgcn_s_barrier();
        if (t + 2 < nt) stage(buf, kv0 + 2*KVB);
    }

    float inv[4];
    #pragma unroll
    for (int r = 0; r < 4; ++r) inv[r] = 1.0f / l[r];
    float* ob = out + ((size_t)bsel*NN + (size_t)(qt*64 + w*16 + g*4))*ND + c;
    #pragma unroll
    for (int r = 0; r < 4; ++r) {
        #pragma unroll
        for (int dt = 0; dt < 16; ++dt)
            ob[(size_t)r*ND + dt*16] = o[dt][r] * inv[r];
    }
}

// ---------------- lowest tier (no workspace) --------------------------------
__global__ __launch_bounds__(256, 2)
void attn_fb(const float* __restrict__ X,
             const int* __restrict__ lenp,
             float* __restrict__ out)
{
    const int b   = blockIdx.y;
    const int qt  = blockIdx.x;
    const int tid = threadIdx.x;
    const int lane = tid & 63;
    const int w = tid >> 6;
    const int g = lane >> 4;
    const int c = lane & 15;

    const bool is64 = (lenp[1] == 0);
    const long long Lb = len_at(lenp, b, is64);

    __shared__ f16 Kl[KVB][264];
    __shared__ f16 Vt2[ND][40];
    __shared__ f16 Pl[4][16][40];

    const float* Xb = X + (size_t)b * NN * ND;

    f16x8 qf[8];
    {
        const float* qp = Xb + (size_t)(qt*64 + w*16 + c) * ND + g*8;
        #pragma unroll
        for (int kk = 0; kk < 8; ++kk) {
            float4 a = *(const float4*)(qp + kk*32);
            float4 d = *(const float4*)(qp + kk*32 + 4);
            f16x8 v;
            v[0]=(f16)a.x; v[1]=(f16)a.y; v[2]=(f16)a.z; v[3]=(f16)a.w;
            v[4]=(f16)d.x; v[5]=(f16)d.y; v[6]=(f16)d.z; v[7]=(f16)d.w;
            qf[kk] = v;
        }
    }

    f32x4 o[16];
    #pragma unroll
    for (int dt = 0; dt < 16; ++dt) o[dt] = (f32x4){0.f,0.f,0.f,0.f};
    float m[4] = {-INFINITY,-INFINITY,-INFINITY,-INFINITY};
    float lr[4] = {0.f,0.f,0.f,0.f};

    const int ntiles = (int)((Lb + KVB - 1) / KVB);
    for (int t = 0; t < ntiles; ++t) {
        const int kv0 = t * KVB;
        __syncthreads();
        #pragma unroll
        for (int it = 0; it < 8; ++it) {
            int idx4 = it*256 + tid;
            int row  = idx4 >> 6;
            int c4   = idx4 & 63;
            float4 v = *(const float4*)(Xb + (size_t)(kv0 + row)*ND + c4*4);
            f16x4 hh; hh[0]=(f16)v.x; hh[1]=(f16)v.y; hh[2]=(f16)v.z; hh[3]=(f16)v.w;
            *(f16x4*)&Kl[row][c4*4] = hh;
        }
        {
            const float* cp = Xb + (size_t)kv0*ND + tid;
            #pragma unroll
            for (int kq = 0; kq < 8; ++kq) {
                f16x4 hh;
                #pragma unroll
                for (int u = 0; u < 4; ++u) hh[u] = (f16)cp[(size_t)(kq*4+u)*ND];
                *(f16x4*)&Vt2[tid][kq*4] = hh;
            }
        }
        __syncthreads();

        f32x4 s0 = (f32x4){0.f,0.f,0.f,0.f};
        f32x4 s1 = (f32x4){0.f,0.f,0.f,0.f};
        #pragma unroll
        for (int kk = 0; kk < 8; ++kk) {
            f16x8 b0 = *(const f16x8*)&Kl[c     ][kk*32 + g*8];
            f16x8 b1 = *(const f16x8*)&Kl[16 + c][kk*32 + g*8];
            s0 = __builtin_amdgcn_mfma_f32_16x16x32_f16(qf[kk], b0, s0, 0, 0, 0);
            s1 = __builtin_amdgcn_mfma_f32_16x16x32_f16(qf[kk], b1, s1, 0, 0, 0);
        }

        const float NEG = -1e30f;
        if (kv0 + c >= Lb)      { s0[0]=NEG; s0[1]=NEG; s0[2]=NEG; s0[3]=NEG; }
        if (kv0 + 16 + c >= Lb) { s1[0]=NEG; s1[1]=NEG; s1[2]=NEG; s1[3]=NEG; }

        float mx[4], mn[4], sc[4], p0[4], p1[4], rs[4];
        #pragma unroll
        for (int r = 0; r < 4; ++r) mx[r] = fmaxf(s0[r], s1[r]);
        #pragma unroll
        for (int off = 8; off >= 1; off >>= 1) {
            #pragma unroll
            for (int r = 0; r < 4; ++r)
                mx[r] = fmaxf(mx[r], __shfl_xor(mx[r], off, 64));
        }
        #pragma unroll
        for (int r = 0; r < 4; ++r) {
            mn[r] = fmaxf(m[r], mx[r]);
            sc[r] = __expf(m[r] - mn[r]);
            p0[r] = __expf(s0[r] - mn[r]);
            p1[r] = __expf(s1[r] - mn[r]);
            rs[r] = p0[r] + p1[r];
        }
        #pragma unroll
        for (int off = 8; off >= 1; off >>= 1) {
            #pragma unroll
            for (int r = 0; r < 4; ++r)
                rs[r] += __shfl_xor(rs[r], off, 64);
        }
        bool chg = (sc[0]!=1.f) | (sc[1]!=1.f) | (sc[2]!=1.f) | (sc[3]!=1.f);
        if (__any(chg)) {
            #pragma unroll
            for (int dt = 0; dt < 16; ++dt) {
                o[dt][0]*=sc[0]; o[dt][1]*=sc[1]; o[dt][2]*=sc[2]; o[dt][3]*=sc[3];
            }
        }
        #pragma unroll
        for (int r = 0; r < 4; ++r) { lr[r] = lr[r]*sc[r] + rs[r]; m[r] = mn[r]; }

        #pragma unroll
        for (int r = 0; r < 4; ++r) {
            Pl[w][g*4+r][c]      = (f16)p0[r];
            Pl[w][g*4+r][16 + c] = (f16)p1[r];
        }
        f16x8 pf = *(const f16x8*)&Pl[w][c][g*8];

        #pragma unroll
        for (int dt = 0; dt < 16; ++dt) {
            f16x8 vf = *(const f16x8*)&Vt2[dt*16 + c][g*8];
            o[dt] = __builtin_amdgcn_mfma_f32_16x16x32_f16(pf, vf, o[dt], 0, 0, 0);
        }
    }

    float inv[4];
    #pragma unroll
    for (int r = 0; r < 4; ++r) inv[r] = 1.0f / lr[r];
    float* ob = out + ((size_t)b*NN + (size_t)(qt*64 + w*16 + g*4))*ND + c;
    #pragma unroll
    for (int r = 0; r < 4; ++r) {
        #pragma unroll
        for (int dt = 0; dt < 16; ++dt)
            ob[(size_t)r*ND + dt*16] = o[dt][r] * inv[r];
    }
}

extern "C" void kernel_launch(void* const* d_in, const int* in_sizes, int n_in,
                              void* d_out, int out_size, void* d_ws, size_t ws_size,
                              hipStream_t stream) {
    const float* X    = (const float*)d_in[0];
    const int*   lenp = (const int*)d_in[1];
    float*       out  = (float*)d_out;

    const size_t need_base  = XSZ * 2 * 2;                    // Xh + Xt (f16)
    const size_t need_split = need_base + XSZ * 2 * 2         // + Op[2] (f16)
                              + (size_t)2 * NB * NN * 4;      // + Sl (f32)
    if (ws_size >= need_split) {
        f16* Xh = (f16*)d_ws;
        f16* Xt = Xh + XSZ;
        f16* Op = Xt + XSZ;
        float* Sl = (float*)(Op + 2*XSZ);
        hipLaunchKernelGGL(prep, dim3(NN/64, ND/64, NB), dim3(256), 0, stream, X, Xh, Xt);
        hipLaunchKernelGGL(attn9, dim3(512), dim3(256), 0, stream, Xh, Xt, lenp, Op, Sl);
        hipLaunchKernelGGL(merge, dim3(NB*NN/8), dim3(256), 0, stream, Op, Sl, lenp, out);
    } else if (ws_size >= need_base) {
        f16* Xh = (f16*)d_ws;
        f16* Xt = Xh + XSZ;
        hipLaunchKernelGGL(prep, dim3(NN/64, ND/64, NB), dim3(256), 0, stream, X, Xh, Xt);
        hipLaunchKernelGGL(attn4, dim3(512), dim3(256), 0, stream, Xh, Xt, lenp, out);
    } else {
        hipLaunchKernelGGL(attn_fb, dim3(NN/64, NB), dim3(256), 0, stream, X, lenp, out);
    }
}